// Round 1
// baseline (329.735 us; speedup 1.0000x reference)
//
#include <hip/hip_runtime.h>
#include <hip/hip_bf16.h>
#include <stdint.h>

#define M_DIM 4096
#define N_DIM 4096
#define K_DIM 4096

typedef __bf16 bf16x8 __attribute__((ext_vector_type(8)));
typedef float  f32x4  __attribute__((ext_vector_type(4)));

// ---------------- amax reduction ----------------
__global__ __launch_bounds__(256) void amax_kernel(const float* __restrict__ in,
                                                   unsigned int* __restrict__ out,
                                                   int n4) {
    float m = 0.f;
    int idx = blockIdx.x * blockDim.x + threadIdx.x;
    int stride = gridDim.x * blockDim.x;
    const float4* in4 = (const float4*)in;
    for (int i = idx; i < n4; i += stride) {
        float4 v = in4[i];
        m = fmaxf(m, fmaxf(fmaxf(fabsf(v.x), fabsf(v.y)), fmaxf(fabsf(v.z), fabsf(v.w))));
    }
#pragma unroll
    for (int off = 32; off > 0; off >>= 1)
        m = fmaxf(m, __shfl_down(m, off, 64));
    if ((threadIdx.x & 63) == 0)
        atomicMax(out, __float_as_uint(m));   // non-negative floats order as uints
}

// ---------------- quant-dequant ----------------
__device__ __forceinline__ float round_e4m3(float v) {
    // v in [0, 448]; RNE to e4m3fn grid (incl. subnormals, ulp=2^-9 below 2^-6)
    if (!(v > 0.f)) return 0.f;
    uint32_t u = __float_as_uint(v);
    int e = (int)(u >> 23) - 127;      // floor(log2 v)
    if (e < -6) e = -6;
    float ulp = __uint_as_float((uint32_t)(e - 3 + 127) << 23);  // 2^(e-3)
    return rintf(v / ulp) * ulp;       // exact div/mul by pow2; rintf = RNE
}

__device__ __forceinline__ float round_e2m1_mag(float a) {
    // a = min(|v|,6). Reference uses searchsorted(mids, a, side='left'):
    // idx = #(mids < a)  -> strict '>' compares (ties round toward zero).
    float q = 0.f;
    q = (a > 0.25f) ? 0.5f : q;
    q = (a > 0.75f) ? 1.0f : q;
    q = (a > 1.25f) ? 1.5f : q;
    q = (a > 1.75f) ? 2.0f : q;
    q = (a > 2.5f)  ? 3.0f : q;
    q = (a > 3.5f)  ? 4.0f : q;
    q = (a > 4.5f)  ? 5.0f : q;
    q = (a > 5.5f)  ? 6.0f : q;
    return q;
}

__global__ __launch_bounds__(256) void quant_kernel(const float* __restrict__ in,
                                                    unsigned short* __restrict__ out,
                                                    const unsigned int* __restrict__ amax_bits) {
    float gmax = fmaxf(__uint_as_float(*amax_bits), 1e-12f);
    float gsf  = 2688.0f / gmax;                 // 448*6/amax
    int t = blockIdx.x * blockDim.x + threadIdx.x;   // one 16-elem block per thread
    const float4* src = (const float4*)in + (size_t)t * 4;
    float4 v0 = src[0], v1 = src[1], v2 = src[2], v3 = src[3];
    float vals[16];
    vals[0]=v0.x; vals[1]=v0.y; vals[2]=v0.z; vals[3]=v0.w;
    vals[4]=v1.x; vals[5]=v1.y; vals[6]=v1.z; vals[7]=v1.w;
    vals[8]=v2.x; vals[9]=v2.y; vals[10]=v2.z; vals[11]=v2.w;
    vals[12]=v3.x; vals[13]=v3.y; vals[14]=v3.z; vals[15]=v3.w;

    float am = 0.f;
#pragma unroll
    for (int i = 0; i < 16; i++) am = fmaxf(am, fabsf(vals[i]));

    float sf  = round_e4m3(fminf(fmaxf(am * gsf / 6.0f, 0.f), 448.0f));
    float inv = (sf > 0.f) ? (gsf / sf) : 0.f;

    unsigned int o[8];
#pragma unroll
    for (int i = 0; i < 8; i++) {
        unsigned int pair = 0;
#pragma unroll
        for (int h = 0; h < 2; h++) {
            float x = vals[i * 2 + h] * inv;
            float a = fminf(fabsf(x), 6.0f);
            float q = round_e2m1_mag(a);
            float th = copysignf(q, x) * sf;    // exactly bf16-representable
            pair |= (__float_as_uint(th) >> 16) << (16 * h);
        }
        o[i] = pair;
    }
    uint4* dst = (uint4*)(out + (size_t)t * 16);
    dst[0] = make_uint4(o[0], o[1], o[2], o[3]);
    dst[1] = make_uint4(o[4], o[5], o[6], o[7]);
}

// ---------------- bf16 GEMM: C = (A[M,K] * B[N,K]^T) * alpha ----------------
#define BM 128
#define BN 128
#define BK 32

__global__ __launch_bounds__(256) void gemm_kernel(const unsigned short* __restrict__ A,  // x_hat
                                                   const unsigned short* __restrict__ B,  // w_hat
                                                   float* __restrict__ C,
                                                   const unsigned int* __restrict__ amax_bits) {
    __shared__ alignas(16) unsigned short lds_a[BM * BK];
    __shared__ alignas(16) unsigned short lds_b[BN * BK];

    int tid  = threadIdx.x;
    int lane = tid & 63;
    int wid  = tid >> 6;             // 0..3
    int brow = blockIdx.y * BM;
    int bcol = blockIdx.x * BN;
    int wr   = (wid >> 1) * 64;      // wave's row offset in tile
    int wc   = (wid & 1) * 64;       // wave's col offset in tile

    f32x4 acc[4][4];
#pragma unroll
    for (int m = 0; m < 4; m++)
#pragma unroll
        for (int n = 0; n < 4; n++)
#pragma unroll
            for (int j = 0; j < 4; j++) acc[m][n][j] = 0.f;

    int lrow = lane >> 2;            // 0..15 (row within 16-row chunk)
    int lcol = (lane & 3) * 8;       // 0,8,16,24 (bf16 col)

    for (int k0 = 0; k0 < K_DIM; k0 += BK) {
#pragma unroll
        for (int i = 0; i < 2; i++) {
            int c    = wid + i * 4;                  // chunk 0..7 (16 rows each)
            int grow = c * 16 + lrow;
            const unsigned short* ga = A + (size_t)(brow + grow) * K_DIM + k0 + lcol;
            const unsigned short* gb = B + (size_t)(bcol + grow) * K_DIM + k0 + lcol;
            __builtin_amdgcn_global_load_lds(
                (const __attribute__((address_space(1))) unsigned int*)ga,
                (__attribute__((address_space(3))) unsigned int*)(lds_a + c * 512), 16, 0, 0);
            __builtin_amdgcn_global_load_lds(
                (const __attribute__((address_space(1))) unsigned int*)gb,
                (__attribute__((address_space(3))) unsigned int*)(lds_b + c * 512), 16, 0, 0);
        }
        __syncthreads();   // drains vmcnt before barrier -> staged data visible

        int kg = (lane >> 4) * 8;    // K-group offset (8 contiguous bf16)
        int r  = lane & 15;
        bf16x8 af[4], bfr[4];
#pragma unroll
        for (int m = 0; m < 4; m++)
            af[m] = *reinterpret_cast<const bf16x8*>(&lds_a[(wr + m * 16 + r) * BK + kg]);
#pragma unroll
        for (int n = 0; n < 4; n++)
            bfr[n] = *reinterpret_cast<const bf16x8*>(&lds_b[(wc + n * 16 + r) * BK + kg]);
#pragma unroll
        for (int m = 0; m < 4; m++)
#pragma unroll
            for (int n = 0; n < 4; n++)
                acc[m][n] = __builtin_amdgcn_mfma_f32_16x16x32_bf16(af[m], bfr[n], acc[m][n], 0, 0, 0);
        __syncthreads();   // all waves done reading before next stage overwrites
    }

    // epilogue: alpha = 1/(gsf_x*gsf_w), C/D layout col=lane&15 row=(lane>>4)*4+j
    float ax = fmaxf(__uint_as_float(amax_bits[0]), 1e-12f);
    float aw = fmaxf(__uint_as_float(amax_bits[1]), 1e-12f);
    float alpha = 1.0f / ((2688.0f / ax) * (2688.0f / aw));
    int r4 = (lane >> 4) * 4;
    int cn = lane & 15;
#pragma unroll
    for (int m = 0; m < 4; m++)
#pragma unroll
        for (int n = 0; n < 4; n++)
#pragma unroll
            for (int j = 0; j < 4; j++) {
                int row = brow + wr + m * 16 + r4 + j;
                int col = bcol + wc + n * 16 + cn;
                C[(size_t)row * N_DIM + col] = acc[m][n][j] * alpha;
            }
}

// ---------------- launch ----------------
extern "C" void kernel_launch(void* const* d_in, const int* in_sizes, int n_in,
                              void* d_out, int out_size, void* d_ws, size_t ws_size,
                              hipStream_t stream) {
    const float* x = (const float*)d_in[0];   // [M,K]
    const float* w = (const float*)d_in[1];   // [N,K]
    float* out = (float*)d_out;               // [M,N]

    unsigned int*   amax  = (unsigned int*)d_ws;                   // [0]=x, [1]=w
    unsigned short* x_hat = (unsigned short*)((char*)d_ws + 256);
    unsigned short* w_hat = x_hat + (size_t)M_DIM * K_DIM;

    hipMemsetAsync(d_ws, 0, 256, stream);  // zero amax slots (ws is poisoned)

    hipLaunchKernelGGL(amax_kernel, dim3(1024), dim3(256), 0, stream, x, amax + 0, M_DIM * K_DIM / 4);
    hipLaunchKernelGGL(amax_kernel, dim3(1024), dim3(256), 0, stream, w, amax + 1, N_DIM * K_DIM / 4);

    hipLaunchKernelGGL(quant_kernel, dim3(M_DIM * K_DIM / 16 / 256), dim3(256), 0, stream, x, x_hat, amax + 0);
    hipLaunchKernelGGL(quant_kernel, dim3(N_DIM * K_DIM / 16 / 256), dim3(256), 0, stream, w, w_hat, amax + 1);

    hipLaunchKernelGGL(gemm_kernel, dim3(N_DIM / BN, M_DIM / BM), dim3(256), 0, stream,
                       x_hat, w_hat, out, (const unsigned int*)d_ws);
}

// Round 2
// 259.361 us; speedup vs baseline: 1.2713x; 1.2713x over previous
//
#include <hip/hip_runtime.h>
#include <hip/hip_bf16.h>
#include <stdint.h>

#define M_DIM 4096
#define N_DIM 4096
#define K_DIM 4096
#define KB 8192              // row bytes (K * 2)

typedef __bf16 bf16x8 __attribute__((ext_vector_type(8)));
typedef float  f32x4  __attribute__((ext_vector_type(4)));

// ---------------- amax reduction ----------------
__global__ __launch_bounds__(256) void amax_kernel(const float* __restrict__ in,
                                                   unsigned int* __restrict__ out,
                                                   int n4) {
    float m = 0.f;
    int idx = blockIdx.x * blockDim.x + threadIdx.x;
    int stride = gridDim.x * blockDim.x;
    const float4* in4 = (const float4*)in;
    for (int i = idx; i < n4; i += stride) {
        float4 v = in4[i];
        m = fmaxf(m, fmaxf(fmaxf(fabsf(v.x), fabsf(v.y)), fmaxf(fabsf(v.z), fabsf(v.w))));
    }
#pragma unroll
    for (int off = 32; off > 0; off >>= 1)
        m = fmaxf(m, __shfl_down(m, off, 64));
    if ((threadIdx.x & 63) == 0)
        atomicMax(out, __float_as_uint(m));   // non-negative floats order as uints
}

// ---------------- quant-dequant ----------------
__device__ __forceinline__ float round_e4m3(float v) {
    if (!(v > 0.f)) return 0.f;
    uint32_t u = __float_as_uint(v);
    int e = (int)(u >> 23) - 127;
    if (e < -6) e = -6;
    float ulp = __uint_as_float((uint32_t)(e - 3 + 127) << 23);  // 2^(e-3)
    return rintf(v / ulp) * ulp;
}

__device__ __forceinline__ float round_e2m1_mag(float a) {
    float q = 0.f;
    q = (a > 0.25f) ? 0.5f : q;
    q = (a > 0.75f) ? 1.0f : q;
    q = (a > 1.25f) ? 1.5f : q;
    q = (a > 1.75f) ? 2.0f : q;
    q = (a > 2.5f)  ? 3.0f : q;
    q = (a > 3.5f)  ? 4.0f : q;
    q = (a > 4.5f)  ? 5.0f : q;
    q = (a > 5.5f)  ? 6.0f : q;
    return q;
}

__global__ __launch_bounds__(256) void quant_kernel(const float* __restrict__ in,
                                                    unsigned short* __restrict__ out,
                                                    const unsigned int* __restrict__ amax_bits) {
    float gmax = fmaxf(__uint_as_float(*amax_bits), 1e-12f);
    float gsf  = 2688.0f / gmax;
    int t = blockIdx.x * blockDim.x + threadIdx.x;
    const float4* src = (const float4*)in + (size_t)t * 4;
    float4 v0 = src[0], v1 = src[1], v2 = src[2], v3 = src[3];
    float vals[16];
    vals[0]=v0.x; vals[1]=v0.y; vals[2]=v0.z; vals[3]=v0.w;
    vals[4]=v1.x; vals[5]=v1.y; vals[6]=v1.z; vals[7]=v1.w;
    vals[8]=v2.x; vals[9]=v2.y; vals[10]=v2.z; vals[11]=v2.w;
    vals[12]=v3.x; vals[13]=v3.y; vals[14]=v3.z; vals[15]=v3.w;

    float am = 0.f;
#pragma unroll
    for (int i = 0; i < 16; i++) am = fmaxf(am, fabsf(vals[i]));

    float sf  = round_e4m3(fminf(fmaxf(am * gsf / 6.0f, 0.f), 448.0f));
    float inv = (sf > 0.f) ? (gsf / sf) : 0.f;

    unsigned int o[8];
#pragma unroll
    for (int i = 0; i < 8; i++) {
        unsigned int pair = 0;
#pragma unroll
        for (int h = 0; h < 2; h++) {
            float x = vals[i * 2 + h] * inv;
            float a = fminf(fabsf(x), 6.0f);
            float q = round_e2m1_mag(a);
            float th = copysignf(q, x) * sf;    // exactly bf16-representable
            pair |= (__float_as_uint(th) >> 16) << (16 * h);
        }
        o[i] = pair;
    }
    uint4* dst = (uint4*)(out + (size_t)t * 16);
    dst[0] = make_uint4(o[0], o[1], o[2], o[3]);
    dst[1] = make_uint4(o[4], o[5], o[6], o[7]);
}

// ---------------- 256x256x64 8-phase bf16 GEMM: C = (A[M,K] * B[N,K]^T) * alpha ----------------
// 8 waves (2Mx4N), per-wave output 128x64. LDS: 2 buf x (A 256x64 | B 256x64) bf16 = 128 KiB.
// Swizzle (involution on byte offsets, bits 4-6 ^= row&7): conflict-free ds_read_b128,
// applied to the GLOBAL source of global_load_lds (linear LDS dest) and to read addrs.
// Counted vmcnt(6): 2 loads/half-tile x 3 half-tiles in flight; waits only at phases 4/8.

__global__ __launch_bounds__(512, 2) void gemm_kernel(const unsigned short* __restrict__ A,
                                                      const unsigned short* __restrict__ B,
                                                      float* __restrict__ C,
                                                      const unsigned int* __restrict__ amax_bits) {
    __shared__ alignas(16) char smem[131072];

    const int tid  = threadIdx.x;
    const int lane = tid & 63;
    const int wid  = tid >> 6;        // 0..7
    const int wr   = wid >> 2;        // 0..1  (row half)
    const int wc   = wid & 3;         // 0..3  (col quarter)

    // XCD-aware swizzle: nwg=256, 256%8==0 -> each XCD gets 32 contiguous blocks (2 grid rows)
    int bid = blockIdx.x;
    int swz = (bid & 7) * 32 + (bid >> 3);
    const int brow = (swz >> 4) * 256;
    const int bcol = (swz & 15) * 256;

    // ---- staging precompute: linear LDS dest (tid*16), pre-swizzled global source ----
    int rowS[2], colS[2], Lr[2];
#pragma unroll
    for (int r = 0; r < 2; ++r) {
        int L = r * 8192 + tid * 16;            // linear byte offset within 16 KiB half-tile
        int b = L ^ (((L >> 7) & 7) << 4);      // logical (unswizzled) byte
        Lr[r] = L;
        rowS[r] = b >> 7;                        // 0..127
        colS[r] = b & 127;                       // byte within row
    }
    const char* Abase = (const char*)A;
    const char* Bbase = (const char*)B;

    // slot: 0 = B.h0, 1 = B.h1, 2 = A.h0, 3 = A.h1   (issue order chosen so each
    // region is staged only at/after the phase where its reads complete)
    auto STAGE = [&](int ts, int slot) {
        const char* mat = (slot >= 2) ? Abase : Bbase;
        int rbase = ((slot >= 2) ? brow : bcol) + ((slot & 1) ? 128 : 0);
        int loff  = (ts & 1) * 65536 + ((slot >= 2) ? 0 : 32768) + ((slot & 1) ? 16384 : 0);
#pragma unroll
        for (int r = 0; r < 2; ++r) {
            const char* gp = mat + (size_t)(rbase + rowS[r]) * KB + ts * 128 + colS[r];
            __builtin_amdgcn_global_load_lds(
                (const __attribute__((address_space(1))) unsigned int*)gp,
                (__attribute__((address_space(3))) unsigned int*)(smem + loff + Lr[r]),
                16, 0, 0);
        }
    };

    // ---- fragment-read precompute ----
    const int lr  = lane & 15;
    const int kg  = lane >> 4;                  // 0..3
    const int swx = (lr & 7) << 4;
    int colA[2];
#pragma unroll
    for (int ks = 0; ks < 2; ++ks) colA[ks] = (ks * 64 + kg * 16) ^ swx;
    int rowAb[8], rowBb[4];
#pragma unroll
    for (int m = 0; m < 8; ++m) rowAb[m] = (wr * 128 + m * 16 + lr) * 128;
#pragma unroll
    for (int n = 0; n < 4; ++n) rowBb[n] = 32768 + (wc * 64 + n * 16 + lr) * 128;

    bf16x8 aR[4][2];          // current A m-group (time-shared)
    bf16x8 bR[4][2];          // all 4 n-frags resident
    f32x4  acc[8][4];
#pragma unroll
    for (int m = 0; m < 8; ++m)
#pragma unroll
        for (int n = 0; n < 4; ++n)
#pragma unroll
            for (int j = 0; j < 4; ++j) acc[m][n][j] = 0.f;

    auto LDA = [&](int bufo, int mg) {
#pragma unroll
        for (int mm = 0; mm < 4; ++mm)
#pragma unroll
            for (int ks = 0; ks < 2; ++ks)
                aR[mm][ks] = *(const bf16x8*)(smem + bufo + rowAb[mg * 4 + mm] + colA[ks]);
    };
    auto LDB = [&](int bufo, int ng) {
#pragma unroll
        for (int nn = 0; nn < 2; ++nn)
#pragma unroll
            for (int ks = 0; ks < 2; ++ks)
                bR[ng * 2 + nn][ks] = *(const bf16x8*)(smem + bufo + rowBb[ng * 2 + nn] + colA[ks]);
    };
    auto MMA = [&](int mg, int ng) {
        __builtin_amdgcn_s_setprio(1);
#pragma unroll
        for (int ks = 0; ks < 2; ++ks)
#pragma unroll
            for (int mm = 0; mm < 4; ++mm)
#pragma unroll
                for (int nn = 0; nn < 2; ++nn) {
                    int m = mg * 4 + mm, n = ng * 2 + nn;
                    acc[m][n] = __builtin_amdgcn_mfma_f32_16x16x32_bf16(aR[mm][ks], bR[n][ks], acc[m][n], 0, 0, 0);
                }
        __builtin_amdgcn_s_setprio(0);
    };

    // ---- prologue: tile0 all 4 half-tiles, then tile1 slots 0-2 ----
    STAGE(0, 0); STAGE(0, 1); STAGE(0, 2); STAGE(0, 3);
    asm volatile("s_waitcnt vmcnt(4)" ::: "memory");
    STAGE(1, 0); STAGE(1, 1); STAGE(1, 2);
    asm volatile("s_waitcnt vmcnt(6)" ::: "memory");   // tile0 fully landed
    __builtin_amdgcn_s_barrier();

    // ---- main loop: 32 iters x 2 K-tiles, 8 phases/iter ----
#pragma unroll 1
    for (int i = 0; i < 32; ++i) {
        int t0 = 2 * i;
        int n2 = (t0 + 2 < 64) ? t0 + 2 : 63;   // clamped restage = identical bytes, safe
        int n3 = (t0 + 3 < 64) ? t0 + 3 : 63;

        // ======== tile t0 (buf 0) ========
        LDA(0, 0); LDB(0, 0); STAGE(t0 + 1, 3);                 // P1
        __builtin_amdgcn_s_barrier();
        asm volatile("s_waitcnt lgkmcnt(0)" ::: "memory");
        MMA(0, 0);
        __builtin_amdgcn_s_barrier();

        LDB(0, 1); STAGE(n2, 0);                                 // P2
        __builtin_amdgcn_s_barrier();
        asm volatile("s_waitcnt lgkmcnt(0)" ::: "memory");
        MMA(0, 1);
        __builtin_amdgcn_s_barrier();

        LDA(0, 1); STAGE(n2, 1);                                 // P3
        __builtin_amdgcn_s_barrier();
        asm volatile("s_waitcnt lgkmcnt(0)" ::: "memory");
        MMA(1, 1);
        __builtin_amdgcn_s_barrier();

        STAGE(n2, 2);                                            // P4
        asm volatile("s_waitcnt vmcnt(6)" ::: "memory");         // tile t0+1 landed
        __builtin_amdgcn_s_barrier();
        MMA(1, 0);
        __builtin_amdgcn_s_barrier();

        // ======== tile t0+1 (buf 65536) ========
        LDA(65536, 0); LDB(65536, 0); STAGE(n2, 3);              // P5
        __builtin_amdgcn_s_barrier();
        asm volatile("s_waitcnt lgkmcnt(0)" ::: "memory");
        MMA(0, 0);
        __builtin_amdgcn_s_barrier();

        LDB(65536, 1); STAGE(n3, 0);                             // P6
        __builtin_amdgcn_s_barrier();
        asm volatile("s_waitcnt lgkmcnt(0)" ::: "memory");
        MMA(0, 1);
        __builtin_amdgcn_s_barrier();

        LDA(65536, 1); STAGE(n3, 1);                             // P7
        __builtin_amdgcn_s_barrier();
        asm volatile("s_waitcnt lgkmcnt(0)" ::: "memory");
        MMA(1, 1);
        __builtin_amdgcn_s_barrier();

        STAGE(n3, 2);                                            // P8
        asm volatile("s_waitcnt vmcnt(6)" ::: "memory");         // tile t0+2 landed
        __builtin_amdgcn_s_barrier();
        MMA(1, 0);
        __builtin_amdgcn_s_barrier();
    }

    // ---- epilogue ----
    float ax = fmaxf(__uint_as_float(amax_bits[0]), 1e-12f);
    float aw = fmaxf(__uint_as_float(amax_bits[1]), 1e-12f);
    float alpha = 1.0f / ((2688.0f / ax) * (2688.0f / aw));
    const int r4 = kg * 4;
    const int cn = lane & 15;
#pragma unroll
    for (int m = 0; m < 8; ++m)
#pragma unroll
        for (int n = 0; n < 4; ++n)
#pragma unroll
            for (int j = 0; j < 4; ++j) {
                int row = brow + wr * 128 + m * 16 + r4 + j;
                int col = bcol + wc * 64 + n * 16 + cn;
                C[(size_t)row * N_DIM + col] = acc[m][n][j] * alpha;
            }
}

// ---------------- launch ----------------
extern "C" void kernel_launch(void* const* d_in, const int* in_sizes, int n_in,
                              void* d_out, int out_size, void* d_ws, size_t ws_size,
                              hipStream_t stream) {
    const float* x = (const float*)d_in[0];   // [M,K]
    const float* w = (const float*)d_in[1];   // [N,K]
    float* out = (float*)d_out;               // [M,N]

    unsigned int*   amax  = (unsigned int*)d_ws;                   // [0]=x, [1]=w
    unsigned short* x_hat = (unsigned short*)((char*)d_ws + 256);
    unsigned short* w_hat = x_hat + (size_t)M_DIM * K_DIM;

    hipMemsetAsync(d_ws, 0, 256, stream);  // zero amax slots (ws is poisoned)

    hipLaunchKernelGGL(amax_kernel, dim3(1024), dim3(256), 0, stream, x, amax + 0, M_DIM * K_DIM / 4);
    hipLaunchKernelGGL(amax_kernel, dim3(1024), dim3(256), 0, stream, w, amax + 1, N_DIM * K_DIM / 4);

    hipLaunchKernelGGL(quant_kernel, dim3(M_DIM * K_DIM / 16 / 256), dim3(256), 0, stream, x, x_hat, amax + 0);
    hipLaunchKernelGGL(quant_kernel, dim3(N_DIM * K_DIM / 16 / 256), dim3(256), 0, stream, w, w_hat, amax + 1);

    hipLaunchKernelGGL(gemm_kernel, dim3(256), dim3(512), 0, stream,
                       x_hat, w_hat, out, (const unsigned int*)d_ws);
}

// Round 4
// 180.960 us; speedup vs baseline: 1.8221x; 1.4333x over previous
//
#include <hip/hip_runtime.h>
#include <hip/hip_bf16.h>
#include <stdint.h>

#define M_DIM 4096
#define N_DIM 4096
#define K_DIM 4096
#define KB 8192              // row bytes (K * 2)

typedef __bf16 bf16x8 __attribute__((ext_vector_type(8)));
typedef float  f32x4  __attribute__((ext_vector_type(4)));

// ---------------- fused amax (both tensors, 1 dispatch) ----------------
// blocks [0,1024): x -> out[0]; [1024,2048): w -> out[1]
// Per tensor: 262144 threads x 16 float4 = 4M float4 = 16M floats (FULL coverage;
// round-3 bug was 4 loads/thread = 1/4 coverage -> clipped absmax 36.75).
__global__ __launch_bounds__(256) void amax2_kernel(const float* __restrict__ x,
                                                    const float* __restrict__ w,
                                                    unsigned int* __restrict__ out) {
    __shared__ float red[4];
    const int half = blockIdx.x >> 10;
    const float4* in4 = (const float4*)(half ? w : x);
    const int lid = (blockIdx.x & 1023) * 256 + threadIdx.x;   // 0..262143
    const int S = 1024 * 256;                                   // 262144 float4 stride
    float m0 = 0.f, m1 = 0.f, m2 = 0.f, m3 = 0.f;
#pragma unroll
    for (int k = 0; k < 4; ++k) {
        float4 a = in4[lid + (4 * k + 0) * S];
        float4 b = in4[lid + (4 * k + 1) * S];
        float4 c = in4[lid + (4 * k + 2) * S];
        float4 d = in4[lid + (4 * k + 3) * S];
        m0 = fmaxf(m0, fmaxf(fmaxf(fabsf(a.x), fabsf(a.y)), fmaxf(fabsf(a.z), fabsf(a.w))));
        m1 = fmaxf(m1, fmaxf(fmaxf(fabsf(b.x), fabsf(b.y)), fmaxf(fabsf(b.z), fabsf(b.w))));
        m2 = fmaxf(m2, fmaxf(fmaxf(fabsf(c.x), fabsf(c.y)), fmaxf(fabsf(c.z), fabsf(c.w))));
        m3 = fmaxf(m3, fmaxf(fmaxf(fabsf(d.x), fabsf(d.y)), fmaxf(fabsf(d.z), fabsf(d.w))));
    }
    float m = fmaxf(fmaxf(m0, m1), fmaxf(m2, m3));
#pragma unroll
    for (int off = 32; off > 0; off >>= 1)
        m = fmaxf(m, __shfl_xor(m, off, 64));
    if ((threadIdx.x & 63) == 0) red[threadIdx.x >> 6] = m;
    __syncthreads();
    if (threadIdx.x == 0) {
        float r = fmaxf(fmaxf(red[0], red[1]), fmaxf(red[2], red[3]));
        atomicMax(out + half, __float_as_uint(r));   // uint order == float order (v>=0)
    }
}

// ---------------- quant-dequant helpers ----------------
__device__ __forceinline__ float round_e4m3(float v) {
    // v in [0,448]; RNE to e4m3fn grid. ulp = 2^(e-3) (e clamped at -6 for subnormals).
    if (!(v > 0.f)) return 0.f;
    uint32_t u = __float_as_uint(v);
    int e = (int)(u >> 23) - 127;
    if (e < -6) e = -6;
    float ulp     = __uint_as_float((uint32_t)(e - 3 + 127) << 23);
    float inv_ulp = __uint_as_float((uint32_t)(3 - e + 127) << 23);
    return rintf(v * inv_ulp) * ulp;   // pow2 scaling exact; rintf = RNE
}

__device__ __forceinline__ float round_e2m1_mag(float a) {
    // searchsorted(mids, a, side='left') semantics: strict '>', ties toward zero
    float q = 0.f;
    q = (a > 0.25f) ? 0.5f : q;
    q = (a > 0.75f) ? 1.0f : q;
    q = (a > 1.25f) ? 1.5f : q;
    q = (a > 1.75f) ? 2.0f : q;
    q = (a > 2.5f)  ? 3.0f : q;
    q = (a > 3.5f)  ? 4.0f : q;
    q = (a > 4.5f)  ? 5.0f : q;
    q = (a > 5.5f)  ? 6.0f : q;
    return q;
}

__device__ __forceinline__ unsigned int pack2(float va, float vb, float inv, float sf) {
    float xa = va * inv, xb = vb * inv;
    float qa = round_e2m1_mag(fminf(fabsf(xa), 6.f));
    float qb = round_e2m1_mag(fminf(fabsf(xb), 6.f));
    float ta = copysignf(qa, xa) * sf;   // exactly bf16-representable (<=7 sig bits)
    float tb = copysignf(qb, xb) * sf;
    return (__float_as_uint(ta) >> 16) | ((__float_as_uint(tb) >> 16) << 16);
}

// ---------------- fused quant (both tensors, 1 dispatch) ----------------
// 4-lane cooperative: lane loads ONE float4 (coalesced 16B/lane), quad-max via
// 2x shfl_xor gives the 16-block amax, lane quantizes its 4 vals, stores 8B.
// Coverage: 1M threads x 8 iters = 8M float4 = both tensors. Quad (4 consecutive
// lanes) = 16 consecutive, 16-aligned floats since li is 4-aligned per quad.
__global__ __launch_bounds__(256) void quant2_kernel(const float* __restrict__ x,
                                                     const float* __restrict__ w,
                                                     unsigned short* __restrict__ xq,
                                                     unsigned short* __restrict__ wq,
                                                     const unsigned int* __restrict__ amax_bits) {
    const float gx = 2688.0f / fmaxf(__uint_as_float(amax_bits[0]), 1e-12f);
    const float gw = 2688.0f / fmaxf(__uint_as_float(amax_bits[1]), 1e-12f);
    const int t0 = blockIdx.x * 256 + threadIdx.x;    // 0..(1M-1)
    const int S = 4096 * 256;                          // 1M threads
#pragma unroll
    for (int it = 0; it < 8; ++it) {
        const bool isx = (it < 4);                     // compile-time under unroll
        const float4* src = (const float4*)(isx ? x : w);
        unsigned short* dst = isx ? xq : wq;
        const float gsf = isx ? gx : gw;
        const int li = t0 + (isx ? it : it - 4) * S;   // 0..4M-1 within tensor
        float4 v = src[li];
        float am = fmaxf(fmaxf(fabsf(v.x), fabsf(v.y)), fmaxf(fabsf(v.z), fabsf(v.w)));
        am = fmaxf(am, __shfl_xor(am, 1, 64));
        am = fmaxf(am, __shfl_xor(am, 2, 64));         // 16-block amax (4-lane group)
        float sf  = round_e4m3(fminf(fmaxf(am * gsf / 6.0f, 0.f), 448.0f));
        float inv = (sf > 0.f) ? (gsf / sf) : 0.f;
        uint2 o;
        o.x = pack2(v.x, v.y, inv, sf);
        o.y = pack2(v.z, v.w, inv, sf);
        *(uint2*)(dst + (size_t)li * 4) = o;
    }
}

// ---------------- 256x256x64 8-phase bf16 GEMM: C = (A[M,K] * B[N,K]^T) * alpha ----------------
// 8 waves (2Mx4N), per-wave output 128x64. LDS: 2 buf x (A 256x64 | B 256x64) bf16 = 128 KiB.
// Swizzle (involution on byte offsets, bits 4-6 ^= row&7): conflict-free ds_read_b128,
// applied to the GLOBAL source of global_load_lds (linear LDS dest) and to read addrs.
// Counted vmcnt(6): 2 loads/half-tile x 3 half-tiles in flight; waits only at phases 4/8.

__global__ __launch_bounds__(512, 2) void gemm_kernel(const unsigned short* __restrict__ A,
                                                      const unsigned short* __restrict__ B,
                                                      float* __restrict__ C,
                                                      const unsigned int* __restrict__ amax_bits) {
    __shared__ alignas(16) char smem[131072];

    const int tid  = threadIdx.x;
    const int lane = tid & 63;
    const int wid  = tid >> 6;        // 0..7
    const int wr   = wid >> 2;        // 0..1  (row half)
    const int wc   = wid & 3;         // 0..3  (col quarter)

    // XCD-aware swizzle: nwg=256, 256%8==0 -> each XCD gets 32 contiguous blocks (2 grid rows)
    int bid = blockIdx.x;
    int swz = (bid & 7) * 32 + (bid >> 3);
    const int brow = (swz >> 4) * 256;
    const int bcol = (swz & 15) * 256;

    // ---- staging precompute: linear LDS dest (tid*16), pre-swizzled global source ----
    int rowS[2], colS[2], Lr[2];
#pragma unroll
    for (int r = 0; r < 2; ++r) {
        int L = r * 8192 + tid * 16;            // linear byte offset within 16 KiB half-tile
        int b = L ^ (((L >> 7) & 7) << 4);      // logical (unswizzled) byte
        Lr[r] = L;
        rowS[r] = b >> 7;                        // 0..127
        colS[r] = b & 127;                       // byte within row
    }
    const char* Abase = (const char*)A;
    const char* Bbase = (const char*)B;

    // slot: 0 = B.h0, 1 = B.h1, 2 = A.h0, 3 = A.h1
    auto STAGE = [&](int ts, int slot) {
        const char* mat = (slot >= 2) ? Abase : Bbase;
        int rbase = ((slot >= 2) ? brow : bcol) + ((slot & 1) ? 128 : 0);
        int loff  = (ts & 1) * 65536 + ((slot >= 2) ? 0 : 32768) + ((slot & 1) ? 16384 : 0);
#pragma unroll
        for (int r = 0; r < 2; ++r) {
            const char* gp = mat + (size_t)(rbase + rowS[r]) * KB + ts * 128 + colS[r];
            __builtin_amdgcn_global_load_lds(
                (const __attribute__((address_space(1))) unsigned int*)gp,
                (__attribute__((address_space(3))) unsigned int*)(smem + loff + Lr[r]),
                16, 0, 0);
        }
    };

    // ---- fragment-read precompute ----
    const int lr  = lane & 15;
    const int kg  = lane >> 4;                  // 0..3
    const int swx = (lr & 7) << 4;
    int colA[2];
#pragma unroll
    for (int ks = 0; ks < 2; ++ks) colA[ks] = (ks * 64 + kg * 16) ^ swx;
    int rowAb[8], rowBb[4];
#pragma unroll
    for (int m = 0; m < 8; ++m) rowAb[m] = (wr * 128 + m * 16 + lr) * 128;
#pragma unroll
    for (int n = 0; n < 4; ++n) rowBb[n] = 32768 + (wc * 64 + n * 16 + lr) * 128;

    bf16x8 aR[4][2];          // current A m-group (time-shared)
    bf16x8 bR[4][2];          // all 4 n-frags resident
    f32x4  acc[8][4];
#pragma unroll
    for (int m = 0; m < 8; ++m)
#pragma unroll
        for (int n = 0; n < 4; ++n)
#pragma unroll
            for (int j = 0; j < 4; ++j) acc[m][n][j] = 0.f;

    auto LDA = [&](int bufo, int mg) {
#pragma unroll
        for (int mm = 0; mm < 4; ++mm)
#pragma unroll
            for (int ks = 0; ks < 2; ++ks)
                aR[mm][ks] = *(const bf16x8*)(smem + bufo + rowAb[mg * 4 + mm] + colA[ks]);
    };
    auto LDB = [&](int bufo, int ng) {
#pragma unroll
        for (int nn = 0; nn < 2; ++nn)
#pragma unroll
            for (int ks = 0; ks < 2; ++ks)
                bR[ng * 2 + nn][ks] = *(const bf16x8*)(smem + bufo + rowBb[ng * 2 + nn] + colA[ks]);
    };
    auto MMA = [&](int mg, int ng) {
        __builtin_amdgcn_s_setprio(1);
#pragma unroll
        for (int ks = 0; ks < 2; ++ks)
#pragma unroll
            for (int mm = 0; mm < 4; ++mm)
#pragma unroll
                for (int nn = 0; nn < 2; ++nn) {
                    int m = mg * 4 + mm, n = ng * 2 + nn;
                    acc[m][n] = __builtin_amdgcn_mfma_f32_16x16x32_bf16(aR[mm][ks], bR[n][ks], acc[m][n], 0, 0, 0);
                }
        __builtin_amdgcn_s_setprio(0);
    };

    // ---- prologue: tile0 all 4 half-tiles, then tile1 slots 0-2 ----
    STAGE(0, 0); STAGE(0, 1); STAGE(0, 2); STAGE(0, 3);
    asm volatile("s_waitcnt vmcnt(4)" ::: "memory");
    STAGE(1, 0); STAGE(1, 1); STAGE(1, 2);
    asm volatile("s_waitcnt vmcnt(6)" ::: "memory");   // tile0 fully landed
    __builtin_amdgcn_s_barrier();

    // ---- main loop: 32 iters x 2 K-tiles, 8 phases/iter ----
#pragma unroll 1
    for (int i = 0; i < 32; ++i) {
        int t0 = 2 * i;
        int n2 = (t0 + 2 < 64) ? t0 + 2 : 63;   // clamped restage = identical bytes, safe
        int n3 = (t0 + 3 < 64) ? t0 + 3 : 63;

        // ======== tile t0 (buf 0) ========
        LDA(0, 0); LDB(0, 0); STAGE(t0 + 1, 3);                 // P1
        __builtin_amdgcn_s_barrier();
        asm volatile("s_waitcnt lgkmcnt(0)" ::: "memory");
        MMA(0, 0);
        __builtin_amdgcn_s_barrier();

        LDB(0, 1); STAGE(n2, 0);                                 // P2
        __builtin_amdgcn_s_barrier();
        asm volatile("s_waitcnt lgkmcnt(0)" ::: "memory");
        MMA(0, 1);
        __builtin_amdgcn_s_barrier();

        LDA(0, 1); STAGE(n2, 1);                                 // P3
        __builtin_amdgcn_s_barrier();
        asm volatile("s_waitcnt lgkmcnt(0)" ::: "memory");
        MMA(1, 1);
        __builtin_amdgcn_s_barrier();

        STAGE(n2, 2);                                            // P4
        asm volatile("s_waitcnt vmcnt(6)" ::: "memory");         // tile t0+1 landed
        __builtin_amdgcn_s_barrier();
        MMA(1, 0);
        __builtin_amdgcn_s_barrier();

        // ======== tile t0+1 (buf 65536) ========
        LDA(65536, 0); LDB(65536, 0); STAGE(n2, 3);              // P5
        __builtin_amdgcn_s_barrier();
        asm volatile("s_waitcnt lgkmcnt(0)" ::: "memory");
        MMA(0, 0);
        __builtin_amdgcn_s_barrier();

        LDB(65536, 1); STAGE(n3, 0);                             // P6
        __builtin_amdgcn_s_barrier();
        asm volatile("s_waitcnt lgkmcnt(0)" ::: "memory");
        MMA(0, 1);
        __builtin_amdgcn_s_barrier();

        LDA(65536, 1); STAGE(n3, 1);                             // P7
        __builtin_amdgcn_s_barrier();
        asm volatile("s_waitcnt lgkmcnt(0)" ::: "memory");
        MMA(1, 1);
        __builtin_amdgcn_s_barrier();

        STAGE(n3, 2);                                            // P8
        asm volatile("s_waitcnt vmcnt(6)" ::: "memory");         // tile t0+2 landed
        __builtin_amdgcn_s_barrier();
        MMA(1, 0);
        __builtin_amdgcn_s_barrier();
    }

    // ---- epilogue ----
    float ax = fmaxf(__uint_as_float(amax_bits[0]), 1e-12f);
    float aw = fmaxf(__uint_as_float(amax_bits[1]), 1e-12f);
    float alpha = 1.0f / ((2688.0f / ax) * (2688.0f / aw));
    const int r4 = kg * 4;
    const int cn = lane & 15;
#pragma unroll
    for (int m = 0; m < 8; ++m)
#pragma unroll
        for (int n = 0; n < 4; ++n)
#pragma unroll
            for (int j = 0; j < 4; ++j) {
                int row = brow + wr * 128 + m * 16 + r4 + j;
                int col = bcol + wc * 64 + n * 16 + cn;
                C[(size_t)row * N_DIM + col] = acc[m][n][j] * alpha;
            }
}

// ---------------- launch ----------------
extern "C" void kernel_launch(void* const* d_in, const int* in_sizes, int n_in,
                              void* d_out, int out_size, void* d_ws, size_t ws_size,
                              hipStream_t stream) {
    const float* x = (const float*)d_in[0];   // [M,K]
    const float* w = (const float*)d_in[1];   // [N,K]
    float* out = (float*)d_out;               // [M,N]

    unsigned int*   amax  = (unsigned int*)d_ws;                   // [0]=x, [1]=w
    unsigned short* x_hat = (unsigned short*)((char*)d_ws + 256);
    unsigned short* w_hat = x_hat + (size_t)M_DIM * K_DIM;

    hipMemsetAsync(d_ws, 0, 256, stream);  // zero amax slots (ws is poisoned)

    hipLaunchKernelGGL(amax2_kernel, dim3(2048), dim3(256), 0, stream, x, w, amax);
    hipLaunchKernelGGL(quant2_kernel, dim3(4096), dim3(256), 0, stream, x, w, x_hat, w_hat,
                       (const unsigned int*)amax);
    hipLaunchKernelGGL(gemm_kernel, dim3(256), dim3(512), 0, stream,
                       x_hat, w_hat, out, (const unsigned int*)d_ws);
}

// Round 5
// 173.983 us; speedup vs baseline: 1.8952x; 1.0401x over previous
//
#include <hip/hip_runtime.h>
#include <hip/hip_bf16.h>
#include <stdint.h>

#define M_DIM 4096
#define N_DIM 4096
#define K_DIM 4096
#define KB 8192              // row bytes (K * 2)

typedef __bf16 bf16x8 __attribute__((ext_vector_type(8)));
typedef float  f32x4  __attribute__((ext_vector_type(4)));

// ---------------- fused amax (both tensors, 1 dispatch) ----------------
__global__ __launch_bounds__(256) void amax2_kernel(const float* __restrict__ x,
                                                    const float* __restrict__ w,
                                                    unsigned int* __restrict__ out) {
    __shared__ float red[4];
    const int half = blockIdx.x >> 10;
    const float4* in4 = (const float4*)(half ? w : x);
    const int lid = (blockIdx.x & 1023) * 256 + threadIdx.x;   // 0..262143
    const int S = 1024 * 256;                                   // 262144 float4 stride
    float m0 = 0.f, m1 = 0.f, m2 = 0.f, m3 = 0.f;
#pragma unroll
    for (int k = 0; k < 4; ++k) {
        float4 a = in4[lid + (4 * k + 0) * S];
        float4 b = in4[lid + (4 * k + 1) * S];
        float4 c = in4[lid + (4 * k + 2) * S];
        float4 d = in4[lid + (4 * k + 3) * S];
        m0 = fmaxf(m0, fmaxf(fmaxf(fabsf(a.x), fabsf(a.y)), fmaxf(fabsf(a.z), fabsf(a.w))));
        m1 = fmaxf(m1, fmaxf(fmaxf(fabsf(b.x), fabsf(b.y)), fmaxf(fabsf(b.z), fabsf(b.w))));
        m2 = fmaxf(m2, fmaxf(fmaxf(fabsf(c.x), fabsf(c.y)), fmaxf(fabsf(c.z), fabsf(c.w))));
        m3 = fmaxf(m3, fmaxf(fmaxf(fabsf(d.x), fabsf(d.y)), fmaxf(fabsf(d.z), fabsf(d.w))));
    }
    float m = fmaxf(fmaxf(m0, m1), fmaxf(m2, m3));
#pragma unroll
    for (int off = 32; off > 0; off >>= 1)
        m = fmaxf(m, __shfl_xor(m, off, 64));
    if ((threadIdx.x & 63) == 0) red[threadIdx.x >> 6] = m;
    __syncthreads();
    if (threadIdx.x == 0) {
        float r = fmaxf(fmaxf(red[0], red[1]), fmaxf(red[2], red[3]));
        atomicMax(out + half, __float_as_uint(r));   // uint order == float order (v>=0)
    }
}

// ---------------- quant-dequant helpers ----------------
__device__ __forceinline__ float round_e4m3(float v) {
    if (!(v > 0.f)) return 0.f;
    uint32_t u = __float_as_uint(v);
    int e = (int)(u >> 23) - 127;
    if (e < -6) e = -6;
    float ulp     = __uint_as_float((uint32_t)(e - 3 + 127) << 23);
    float inv_ulp = __uint_as_float((uint32_t)(3 - e + 127) << 23);
    return rintf(v * inv_ulp) * ulp;   // pow2 scaling exact; rintf = RNE
}

__device__ __forceinline__ float round_e2m1_mag(float a) {
    float q = 0.f;
    q = (a > 0.25f) ? 0.5f : q;
    q = (a > 0.75f) ? 1.0f : q;
    q = (a > 1.25f) ? 1.5f : q;
    q = (a > 1.75f) ? 2.0f : q;
    q = (a > 2.5f)  ? 3.0f : q;
    q = (a > 3.5f)  ? 4.0f : q;
    q = (a > 4.5f)  ? 5.0f : q;
    q = (a > 5.5f)  ? 6.0f : q;
    return q;
}

__device__ __forceinline__ unsigned int pack2(float va, float vb, float inv, float sf) {
    float xa = va * inv, xb = vb * inv;
    float qa = round_e2m1_mag(fminf(fabsf(xa), 6.f));
    float qb = round_e2m1_mag(fminf(fabsf(xb), 6.f));
    float ta = copysignf(qa, xa) * sf;   // exactly bf16-representable (<=7 sig bits)
    float tb = copysignf(qb, xb) * sf;
    return (__float_as_uint(ta) >> 16) | ((__float_as_uint(tb) >> 16) << 16);
}

// ---------------- fused quant (both tensors, 1 dispatch) ----------------
__global__ __launch_bounds__(256) void quant2_kernel(const float* __restrict__ x,
                                                     const float* __restrict__ w,
                                                     unsigned short* __restrict__ xq,
                                                     unsigned short* __restrict__ wq,
                                                     const unsigned int* __restrict__ amax_bits) {
    const float gx = 2688.0f / fmaxf(__uint_as_float(amax_bits[0]), 1e-12f);
    const float gw = 2688.0f / fmaxf(__uint_as_float(amax_bits[1]), 1e-12f);
    const int t0 = blockIdx.x * 256 + threadIdx.x;    // 0..(1M-1)
    const int S = 4096 * 256;                          // 1M threads
#pragma unroll
    for (int it = 0; it < 8; ++it) {
        const bool isx = (it < 4);                     // compile-time under unroll
        const float4* src = (const float4*)(isx ? x : w);
        unsigned short* dst = isx ? xq : wq;
        const float gsf = isx ? gx : gw;
        const int li = t0 + (isx ? it : it - 4) * S;   // 0..4M-1 within tensor
        float4 v = src[li];
        float am = fmaxf(fmaxf(fabsf(v.x), fabsf(v.y)), fmaxf(fabsf(v.z), fabsf(v.w)));
        am = fmaxf(am, __shfl_xor(am, 1, 64));
        am = fmaxf(am, __shfl_xor(am, 2, 64));         // 16-block amax (4-lane group)
        float sf  = round_e4m3(fminf(fmaxf(am * gsf / 6.0f, 0.f), 448.0f));
        float inv = (sf > 0.f) ? (gsf / sf) : 0.f;
        uint2 o;
        o.x = pack2(v.x, v.y, inv, sf);
        o.y = pack2(v.z, v.w, inv, sf);
        *(uint2*)(dst + (size_t)li * 4) = o;
    }
}

// ---------------- 256x256x64 lag-1 pipelined bf16 GEMM ----------------
// 8 waves (2Mx4N), per-wave output 128x64. LDS: 2 buf x (A 256x64 | B 256x64) = 128 KiB.
// LAG-1: phase p issues ds_reads consumed by phase p+1's MFMA (compiler emits
// counted lgkmcnt) -> LDS pipe overlaps MFMA pipe. Per tile (4 phases, 1 barrier each):
//   Ph1: MMA c3(t-1); ds: c0->sA, B-all->bR (WAR after MMA); STAGE(t+1,3)
//   Ph2: ds c1->sB; MMA c0(sA); STAGE(t+2,0)
//   Ph3: ds c2->sA; MMA c1(sB); STAGE(t+2,1)
//   Ph4: ds c3->sB; MMA c2(sA); STAGE(t+2,2); vmcnt(6)
// Reg budget unchanged (B 32 + A 2x16 = 64 frag VGPR): fits 2 waves/SIMD with 128 AGPR acc.
__global__ __launch_bounds__(512, 2) void gemm_kernel(const unsigned short* __restrict__ A,
                                                      const unsigned short* __restrict__ B,
                                                      float* __restrict__ C,
                                                      const unsigned int* __restrict__ amax_bits) {
    __shared__ alignas(16) char smem[131072];

    const int tid  = threadIdx.x;
    const int lane = tid & 63;
    const int wid  = tid >> 6;        // 0..7
    const int wr   = wid >> 2;        // 0..1  (row half)
    const int wc   = wid & 3;         // 0..3  (col quarter)

    // XCD-aware swizzle: 256 blocks % 8 == 0 -> 32 contiguous blocks per XCD
    int bid = blockIdx.x;
    int swz = (bid & 7) * 32 + (bid >> 3);
    const int brow = (swz >> 4) * 256;
    const int bcol = (swz & 15) * 256;

    // ---- staging precompute: linear LDS dest (tid*16), pre-swizzled global source ----
    int rowS[2], colS[2], Lr[2];
#pragma unroll
    for (int r = 0; r < 2; ++r) {
        int L = r * 8192 + tid * 16;
        int b = L ^ (((L >> 7) & 7) << 4);      // inverse of read-side swizzle
        Lr[r] = L;
        rowS[r] = b >> 7;
        colS[r] = b & 127;
    }
    const char* Abase = (const char*)A;
    const char* Bbase = (const char*)B;

    // slot: 0 = B.h0, 1 = B.h1, 2 = A.h0, 3 = A.h1
    auto STAGE = [&](int ts, int slot) {
        const char* mat = (slot >= 2) ? Abase : Bbase;
        int rbase = ((slot >= 2) ? brow : bcol) + ((slot & 1) ? 128 : 0);
        int loff  = (ts & 1) * 65536 + ((slot >= 2) ? 0 : 32768) + ((slot & 1) ? 16384 : 0);
#pragma unroll
        for (int r = 0; r < 2; ++r) {
            const char* gp = mat + (size_t)(rbase + rowS[r]) * KB + ts * 128 + colS[r];
            __builtin_amdgcn_global_load_lds(
                (const __attribute__((address_space(1))) unsigned int*)gp,
                (__attribute__((address_space(3))) unsigned int*)(smem + loff + Lr[r]),
                16, 0, 0);
        }
    };

    // ---- fragment-read precompute ----
    const int lr  = lane & 15;
    const int kg  = lane >> 4;                  // 0..3
    const int swx = (lr & 7) << 4;
    int colA[2];
#pragma unroll
    for (int ks = 0; ks < 2; ++ks) colA[ks] = (ks * 64 + kg * 16) ^ swx;
    int rowAb[8], rowBb[4];
#pragma unroll
    for (int m = 0; m < 8; ++m) rowAb[m] = (wr * 128 + m * 16 + lr) * 128;
#pragma unroll
    for (int n = 0; n < 4; ++n) rowBb[n] = 32768 + (wc * 64 + n * 16 + lr) * 128;

    bf16x8 bR[4][2];                  // all 4 n-frags (single set, reloaded per tile)
    bf16x8 aS0[2][2], aS1[2][2];      // A-chunk ping-pong sets (2 m-frags x 2 ks)
    f32x4  acc[8][4];
#pragma unroll
    for (int m = 0; m < 8; ++m)
#pragma unroll
        for (int n = 0; n < 4; ++n)
#pragma unroll
            for (int j = 0; j < 4; ++j) acc[m][n][j] = 0.f;

    auto LDB_ALL = [&](int bufo) {
#pragma unroll
        for (int n = 0; n < 4; ++n)
#pragma unroll
            for (int ks = 0; ks < 2; ++ks)
                bR[n][ks] = *(const bf16x8*)(smem + bufo + rowBb[n] + colA[ks]);
    };
    auto LDC = [&](int bufo, int ci, bf16x8 (&s)[2][2]) {   // A-chunk ci -> set s
#pragma unroll
        for (int mm = 0; mm < 2; ++mm)
#pragma unroll
            for (int ks = 0; ks < 2; ++ks)
                s[mm][ks] = *(const bf16x8*)(smem + bufo + rowAb[ci * 2 + mm] + colA[ks]);
    };
    auto MMAc = [&](int ci, bf16x8 (&s)[2][2]) {            // 16 MFMA on chunk ci
        __builtin_amdgcn_s_setprio(1);
#pragma unroll
        for (int ks = 0; ks < 2; ++ks)
#pragma unroll
            for (int mm = 0; mm < 2; ++mm)
#pragma unroll
                for (int n = 0; n < 4; ++n)
                    acc[ci * 2 + mm][n] =
                        __builtin_amdgcn_mfma_f32_16x16x32_bf16(s[mm][ks], bR[n][ks], acc[ci * 2 + mm][n], 0, 0, 0);
        __builtin_amdgcn_s_setprio(0);
    };

    // ---- prologue: stage tiles 0,1; peel Ph1(0) (no MMA) ----
    STAGE(0, 0); STAGE(0, 1); STAGE(0, 2); STAGE(0, 3);
    asm volatile("s_waitcnt vmcnt(4)" ::: "memory");
    STAGE(1, 0); STAGE(1, 1); STAGE(1, 2);
    asm volatile("s_waitcnt vmcnt(6)" ::: "memory");   // tile0 fully landed
    __builtin_amdgcn_s_barrier();
    LDC(0, 0, aS0); LDB_ALL(0); STAGE(1, 3);           // Ph1(0)
    __builtin_amdgcn_s_barrier();

    // ---- main loop: 32 iters x 2 K-tiles, 8 single-barrier phases ----
#pragma unroll 1
    for (int i = 0; i < 32; ++i) {
        int e = 2 * i;
        int n2 = (e + 2 < 64) ? e + 2 : 63;   // clamped restage = identical bytes
        int n3 = (e + 3 < 64) ? e + 3 : 63;

        // Ph2(e)
        LDC(0, 1, aS1); MMAc(0, aS0); STAGE(n2, 0);
        __builtin_amdgcn_s_barrier();
        // Ph3(e)
        LDC(0, 2, aS0); MMAc(1, aS1); STAGE(n2, 1);
        __builtin_amdgcn_s_barrier();
        // Ph4(e)
        LDC(0, 3, aS1); MMAc(2, aS0); STAGE(n2, 2);
        asm volatile("s_waitcnt vmcnt(6)" ::: "memory");   // tile e+1 landed
        __builtin_amdgcn_s_barrier();
        // Ph1(e+1): MMA c3(e) BEFORE B reload (reg-WAR orders MFMA before ds_write to bR)
        LDC(65536, 0, aS0); MMAc(3, aS1); LDB_ALL(65536); STAGE(n2, 3);
        __builtin_amdgcn_s_barrier();
        // Ph2(e+1)
        LDC(65536, 1, aS1); MMAc(0, aS0); STAGE(n3, 0);
        __builtin_amdgcn_s_barrier();
        // Ph3(e+1)
        LDC(65536, 2, aS0); MMAc(1, aS1); STAGE(n3, 1);
        __builtin_amdgcn_s_barrier();
        // Ph4(e+1)
        LDC(65536, 3, aS1); MMAc(2, aS0); STAGE(n3, 2);
        asm volatile("s_waitcnt vmcnt(6)" ::: "memory");   // tile e+2 landed
        __builtin_amdgcn_s_barrier();
        // Ph1(e+2): final MMA of tile e+1; loads are next tile's (or harmless stale at i=31)
        LDC(0, 0, aS0); MMAc(3, aS1); LDB_ALL(0); STAGE(n3, 3);
        __builtin_amdgcn_s_barrier();
    }

    // ---- epilogue ----
    float ax = fmaxf(__uint_as_float(amax_bits[0]), 1e-12f);
    float aw = fmaxf(__uint_as_float(amax_bits[1]), 1e-12f);
    float alpha = 1.0f / ((2688.0f / ax) * (2688.0f / aw));
    const int r4 = kg * 4;
    const int cn = lane & 15;
#pragma unroll
    for (int m = 0; m < 8; ++m)
#pragma unroll
        for (int n = 0; n < 4; ++n)
#pragma unroll
            for (int j = 0; j < 4; ++j) {
                int row = brow + wr * 128 + m * 16 + r4 + j;
                int col = bcol + wc * 64 + n * 16 + cn;
                C[(size_t)row * N_DIM + col] = acc[m][n][j] * alpha;
            }
}

// ---------------- launch ----------------
extern "C" void kernel_launch(void* const* d_in, const int* in_sizes, int n_in,
                              void* d_out, int out_size, void* d_ws, size_t ws_size,
                              hipStream_t stream) {
    const float* x = (const float*)d_in[0];   // [M,K]
    const float* w = (const float*)d_in[1];   // [N,K]
    float* out = (float*)d_out;               // [M,N]

    unsigned int*   amax  = (unsigned int*)d_ws;                   // [0]=x, [1]=w
    unsigned short* x_hat = (unsigned short*)((char*)d_ws + 256);
    unsigned short* w_hat = x_hat + (size_t)M_DIM * K_DIM;

    hipMemsetAsync(d_ws, 0, 256, stream);  // zero amax slots (ws is poisoned)

    hipLaunchKernelGGL(amax2_kernel, dim3(2048), dim3(256), 0, stream, x, w, amax);
    hipLaunchKernelGGL(quant2_kernel, dim3(4096), dim3(256), 0, stream, x, w, x_hat, w_hat,
                       (const unsigned int*)amax);
    hipLaunchKernelGGL(gemm_kernel, dim3(256), dim3(512), 0, stream,
                       x_hat, w_hat, out, (const unsigned int*)d_ws);
}